// Round 3
// baseline (960.476 us; speedup 1.0000x reference)
//
#include <hip/hip_runtime.h>

#define B_    64
#define CIN_  3
#define J_    11
#define T_    512
#define CO_   128
#define KPS_  168
#define NLOC_ (B_*J_*T_)   // 360448
#define NSTATF_ 360448.0f

typedef unsigned short u16;
typedef unsigned int   u32;

__device__ __forceinline__ float b2f(u16 u){ union{u32 i; float f;} v; v.i = ((u32)u)<<16; return v.f; }
__device__ __forceinline__ u16 f2b(float f){ union{float f; u32 i;} v; v.f=f; u32 r = v.i + 0x7FFFu + ((v.i>>16)&1u); return (u16)(r>>16); }

// load element i of an EXTERNAL buffer whose dtype is bf16 (BF=true) or fp32 (BF=false)
template<bool BF>
__device__ __forceinline__ float ldx(const void* p, size_t i){
  if constexpr (BF) return b2f(((const u16*)p)[i]);
  else              return ((const float*)p)[i];
}

// DT: detect external dtype from bit patterns of x (random N(0,1) data).
// fp32: bits 7..14 of a word are mantissa bits (uniform) -> ~16% in [100,140].
// bf16 pairs: low half is a bf16 sample of N(0,1) -> exponent in [100,140] w.p. ~1.
__global__ void kdet(const u32* __restrict__ xw, u32* __restrict__ flag){
  __shared__ int cnt;
  if (threadIdx.x==0) cnt=0;
  __syncthreads();
  u32 w = xw[threadIdx.x*4 + 1];
  int e = (int)((w>>7)&0xFFu);
  if (e>=100 && e<=140) atomicAdd(&cnt,1);
  __syncthreads();
  if (threadIdx.x==0) *flag = (cnt>128) ? 1u : 0u;   // 1 = bf16 I/O
}

// K0a: zero stat accumulators (dtype-free)
__global__ __launch_bounds__(256) void k0a_zero(float* __restrict__ statsY, float* __restrict__ statsF){
  const int stride = gridDim.x*blockDim.x;
  const int t0 = blockIdx.x*blockDim.x + threadIdx.x;
  for (int i=t0;i<64*512;i+=stride) statsY[i]=0.f;
  for (int i=t0;i<64*256;i+=stride) statsF[i]=0.f;
}

// K0b: transpose ps_w [128][168] and fus_w [128][256] to [K][128] fp32
template<bool BF>
__global__ __launch_bounds__(256) void k0b_tr(const u32* __restrict__ flag,
    const void* __restrict__ ps_w, const void* __restrict__ fus_w,
    float* __restrict__ psT, float* __restrict__ fusT)
{
  if (*flag != (BF?1u:0u)) return;
  const int stride = gridDim.x*blockDim.x;
  const int t0 = blockIdx.x*blockDim.x + threadIdx.x;
  for (int i=t0;i<128*168;i+=stride){ int o=i/168, k=i-o*168; psT[k*128+o]=ldx<BF>(ps_w,i); }
  for (int i=t0;i<128*256;i+=stride){ int o=i>>8, k=i&255; fusT[k*128+o]=ldx<BF>(fus_w,i); }
}

// one Chen step of the depth-3 signature, c=4, fully unrolled
__device__ __forceinline__ void sigstep(float* S1, float* S2, float* S3, const float* d){
  float e2[16];
  #pragma unroll
  for (int a=0;a<4;a++){
    #pragma unroll
    for (int b=0;b<4;b++) e2[a*4+b] = 0.5f*d[a]*d[b];
  }
  #pragma unroll
  for (int a=0;a<4;a++){
    float s1e = S1[a] + (1.0f/3.0f)*d[a];
    #pragma unroll
    for (int b=0;b<4;b++){
      #pragma unroll
      for (int c=0;c<4;c++){
        S3[a*16+b*4+c] += S2[a*4+b]*d[c] + s1e*e2[b*4+c];
      }
    }
  }
  #pragma unroll
  for (int a=0;a<4;a++){
    #pragma unroll
    for (int b=0;b<4;b++) S2[a*4+b] += S1[a]*d[b] + e2[a*4+b];
  }
  #pragma unroll
  for (int a=0;a<4;a++) S1[a] += d[a];
}

// K1: per 64-location tile (one (b,j), 64 consecutive t): signatures + x_conv + ps conv.
// Y (ws) is ALWAYS bf16 internally.
template<bool BF>
__global__ __launch_bounds__(256) void k1_sig_conv(const u32* __restrict__ flag,
    const void* __restrict__ x, const int* __restrict__ path,
    const void* __restrict__ raw_w, const void* __restrict__ raw_b,
    const void* __restrict__ ps_b, const float* __restrict__ psT,
    u16* __restrict__ Y, float* __restrict__ statsY,
    int locOff, int writeY, int doStats)
{
  if (*flag != (BF?1u:0u)) return;
  __shared__ float sig[KPS_*68];   // [168 sig-ch][64 locs + pad4]; aliased as reduction buf later
  __shared__ float xt[CIN_][70];   // temporal slice with halo 3 (edge-clamped)
  __shared__ float xs[CIN_][3][64];// spatial path joints
  __shared__ float rw[CO_*9];
  __shared__ float rb[CO_];
  __shared__ int   pj[3];

  const int tid = threadIdx.x;
  const int blk = blockIdx.x;
  const int lb  = locOff + blk*64;       // global location base
  const int lbl = blk*64;                // chunk-local location base (Y index)
  const int b   = lb / (J_*T_);
  const int j   = (lb / T_) % J_;
  const int t0  = lb % T_;
  const size_t xbase = (size_t)b*CIN_*J_*T_;

  if (tid < 3) pj[tid] = path[j*3 + tid];
  for (int idx=tid; idx<CIN_*70; idx+=256){
    int c=idx/70, u=idx-c*70;
    int t=t0+u-3; t = t<0?0:(t>T_-1?T_-1:t);
    xt[c][u] = ldx<BF>(x, xbase + (size_t)(c*J_+j)*T_ + t);
  }
  for (int idx=tid; idx<CO_*9; idx+=256) rw[idx]=ldx<BF>(raw_w, idx);
  if (tid < CO_) rb[tid]=ldx<BF>(raw_b, tid);
  __syncthreads();
  for (int idx=tid; idx<CIN_*3*64; idx+=256){
    int c=idx/192, p=(idx>>6)%3, tt=idx&63;
    xs[c][p][tt] = ldx<BF>(x, xbase + (size_t)(c*J_+pj[p])*T_ + t0 + tt);
  }
  __syncthreads();

  // phase B: signatures. wave0 = spatial (L=3), wave1 = temporal (L=7); wave-uniform
  if (tid < 128){
    const bool spf = tid < 64;
    const int  tt  = tid & 63;
    const int  L   = spf ? 3 : 7;
    const float dt = spf ? 0.5f : (1.0f/6.0f);
    float S1[4], S2[16], S3[64];
    #pragma unroll
    for (int i=0;i<4;i++)  S1[i]=0.f;
    #pragma unroll
    for (int i=0;i<16;i++) S2[i]=0.f;
    #pragma unroll
    for (int i=0;i<64;i++) S3[i]=0.f;
    float prv[3], d[4];
    for (int c=0;c<3;c++) prv[c] = spf ? xs[c][0][tt] : xt[c][tt];
    d[0]=0.f; d[1]=prv[0]; d[2]=prv[1]; d[3]=prv[2];
    sigstep(S1,S2,S3,d);
    for (int s=1;s<L;s++){
      d[0]=dt;
      for (int c=0;c<3;c++){ float cv = spf ? xs[c][s][tt] : xt[c][tt+s]; d[c+1]=cv-prv[c]; prv[c]=cv; }
      sigstep(S1,S2,S3,d);
    }
    const int sb = spf ? 0 : 84;
    #pragma unroll
    for (int i=0;i<4;i++)  sig[(sb+i)*68+tt]   = S1[i];
    #pragma unroll
    for (int i=0;i<16;i++) sig[(sb+4+i)*68+tt] = S2[i];
    #pragma unroll
    for (int i=0;i<64;i++) sig[(sb+20+i)*68+tt]= S3[i];
  }
  __syncthreads();

  const int tx = tid & 7;   // loc group: locs tx*8+i
  const int ty = tid >> 3;  // channel group: ch = ty*4+c
  // phase C: x_conv (1x3, zero pad on t)
  float accC[8][4];
  {
    float w[4][9], bia[4];
    #pragma unroll
    for (int c=0;c<4;c++){
      bia[c]=rb[ty*4+c];
      #pragma unroll
      for (int q=0;q<9;q++) w[c][q]=rw[(ty*4+c)*9+q];
    }
    #pragma unroll
    for (int i=0;i<8;i++){
      const int tl=tx*8+i, tg=t0+tl;
      float xv[9];
      #pragma unroll
      for (int cc=0;cc<3;cc++){
        #pragma unroll
        for (int kt=0;kt<3;kt++){
          float v = xt[cc][tl+2+kt];            // x[tg-1+kt], edge-clamped in LDS
          if ((tg==0 && kt==0) || (tg==T_-1 && kt==2)) v=0.f;  // conv uses ZERO pad
          xv[cc*3+kt]=v;
        }
      }
      #pragma unroll
      for (int c=0;c<4;c++){
        float s=bia[c];
        #pragma unroll
        for (int q=0;q<9;q++) s=fmaf(xv[q],w[c][q],s);
        accC[i][c]=s;
      }
    }
  }
  // phase D: ps conv (K=168) from sig LDS; 8 locs x 4 ch per thread
  float accD[8][4];
  #pragma unroll
  for (int i=0;i<8;i++){ accD[i][0]=0.f;accD[i][1]=0.f;accD[i][2]=0.f;accD[i][3]=0.f; }
  const float4* psT4 = reinterpret_cast<const float4*>(psT);
  #pragma unroll 2
  for (int k=0;k<KPS_;k++){
    float4 w4 = psT4[k*32 + ty];
    const float4* sp4 = reinterpret_cast<const float4*>(&sig[k*68 + tx*8]);
    float4 s0 = sp4[0], s1 = sp4[1];
    float sv[8] = {s0.x,s0.y,s0.z,s0.w,s1.x,s1.y,s1.z,s1.w};
    #pragma unroll
    for (int i=0;i<8;i++){
      accD[i][0]=fmaf(sv[i],w4.x,accD[i][0]);
      accD[i][1]=fmaf(sv[i],w4.y,accD[i][1]);
      accD[i][2]=fmaf(sv[i],w4.z,accD[i][2]);
      accD[i][3]=fmaf(sv[i],w4.w,accD[i][3]);
    }
  }
  #pragma unroll
  for (int c=0;c<4;c++){
    float pb=ldx<BF>(ps_b, ty*4+c);
    #pragma unroll
    for (int i=0;i<8;i++) accD[i][c]+=pb;
  }
  // stores: Y[loc][0..127]=x_conv, Y[loc][128..255]=ps conv (bf16, 8B packed)
  if (writeY){
    #pragma unroll
    for (int i=0;i<8;i++){
      u16* yp = Y + (size_t)(lbl + tx*8+i)*256;
      u32 v0=(u32)f2b(accC[i][0]) | ((u32)f2b(accC[i][1])<<16);
      u32 v1=(u32)f2b(accC[i][2]) | ((u32)f2b(accC[i][3])<<16);
      *reinterpret_cast<uint2*>(yp + ty*4) = make_uint2(v0,v1);
      u32 v2=(u32)f2b(accD[i][0]) | ((u32)f2b(accD[i][1])<<16);
      u32 v3=(u32)f2b(accD[i][2]) | ((u32)f2b(accD[i][3])<<16);
      *reinterpret_cast<uint2*>(yp + 128 + ty*4) = make_uint2(v2,v3);
    }
  }
  if (doStats){
    float sums[16];
    #pragma unroll
    for (int c=0;c<4;c++){
      float sC=0,qC=0,sD=0,qD=0;
      #pragma unroll
      for (int i=0;i<8;i++){
        float v=accC[i][c]; sC+=v; qC+=v*v;
        float u=accD[i][c]; sD+=u; qD+=u*u;
      }
      sums[c]=sC; sums[4+c]=qC; sums[8+c]=sD; sums[12+c]=qD;
    }
    __syncthreads();            // everyone done reading sig
    float* red = sig;           // alias: [ty32][tx8][16] = 4096 floats
    #pragma unroll
    for (int q=0;q<16;q++) red[(ty*8+tx)*16+q] = sums[q];
    __syncthreads();
    for (int e=tid*2; e<tid*2+2; e++){
      int tye=e>>4, q=e&15;
      float s=0.f;
      for (int t2=0;t2<8;t2++) s += red[(tye*8+t2)*16+q];
      int ch = (q<8) ? (tye*4+(q&3)) : (128 + tye*4+(q&3));
      int which = (q&7)>>2;
      atomicAdd(&statsY[(blk&63)*512 + ch*2 + which], s);
    }
  }
}

// K2: finalize 256-channel BN scale/shift for Y
template<bool BF>
__global__ __launch_bounds__(256) void k2_finY(const u32* __restrict__ flag,
    const float* __restrict__ statsY,
    const void* __restrict__ raw_g, const void* __restrict__ raw_beta,
    const void* __restrict__ ps_g,  const void* __restrict__ ps_beta,
    float* __restrict__ scaleY, float* __restrict__ shiftY)
{
  if (*flag != (BF?1u:0u)) return;
  int ch = threadIdx.x;
  float s=0.f,q=0.f;
  for (int slot=0;slot<64;slot++){ s+=statsY[slot*512+ch*2]; q+=statsY[slot*512+ch*2+1]; }
  float m = s/NSTATF_;
  float v = q/NSTATF_ - m*m; v = fmaxf(v,0.f);
  float r = rsqrtf(v + 1e-5f);
  float g  = (ch<128)? ldx<BF>(raw_g,ch)    : ldx<BF>(ps_g,ch-128);
  float be = (ch<128)? ldx<BF>(raw_beta,ch) : ldx<BF>(ps_beta,ch-128);
  scaleY[ch]=r*g; shiftY[ch]=be - m*r*g;
}

// K3: fus 1x1 conv. tile 128 locs x 128 ch, K=256 in chunks of 32. BN+ReLU fused into staging.
// F aliases d_out (external dtype).
template<bool BF>
__global__ __launch_bounds__(256) void k3_fus(const u32* __restrict__ flag,
    const u16* __restrict__ Y,
    const float* __restrict__ fusT, const float* __restrict__ scaleY, const float* __restrict__ shiftY,
    const void* __restrict__ fus_b, void* __restrict__ F, float* __restrict__ statsF,
    int locOff)
{
  if (*flag != (BF?1u:0u)) return;
  __shared__ float ylds[128*33];  // [loc][k + pad1]
  __shared__ float wlds[32*128];  // [k][o]; aliased as reduction buf later
  const int tid = threadIdx.x, blk = blockIdx.x;
  const size_t loc0  = (size_t)locOff + (size_t)blk*128;   // global
  const size_t loc0l = (size_t)blk*128;                    // chunk-local (Y)
  const int tx = tid & 15, ty = tid >> 4;   // 16x8 locs, 16x8 chans
  float acc[8][8];
  #pragma unroll
  for (int i=0;i<8;i++){
    #pragma unroll
    for (int jc=0;jc<8;jc++) acc[i][jc]=0.f;
  }
  for (int kb=0;kb<256;kb+=32){
    #pragma unroll
    for (int rep=0;rep<4;rep++){  // w stage: 32x128
      int q = tid + rep*256;
      int k = q>>5, o4 = (q&31)<<2;
      *reinterpret_cast<float4*>(&wlds[(k<<7)+o4]) =
          *reinterpret_cast<const float4*>(&fusT[((size_t)(kb+k)<<7)+o4]);
    }
    #pragma unroll
    for (int rep=0;rep<4;rep++){  // y stage: 128x32, BN+ReLU fused
      int q = tid + rep*256;
      int l = q>>3, kq = (q&7)<<2;
      int ch = kb + kq;
      uint2 u = *reinterpret_cast<const uint2*>(Y + (loc0l + l)*256 + ch);
      float f0=b2f((u16)(u.x&0xffff)), f1=b2f((u16)(u.x>>16));
      float f2v=b2f((u16)(u.y&0xffff)), f3=b2f((u16)(u.y>>16));
      f0 =fmaxf(fmaf(f0 ,scaleY[ch  ],shiftY[ch  ]),0.f);
      f1 =fmaxf(fmaf(f1 ,scaleY[ch+1],shiftY[ch+1]),0.f);
      f2v=fmaxf(fmaf(f2v,scaleY[ch+2],shiftY[ch+2]),0.f);
      f3 =fmaxf(fmaf(f3 ,scaleY[ch+3],shiftY[ch+3]),0.f);
      float* yp=&ylds[l*33+kq];
      yp[0]=f0; yp[1]=f1; yp[2]=f2v; yp[3]=f3;
    }
    __syncthreads();
    for (int k=0;k<32;k++){
      float4 w0 = *reinterpret_cast<const float4*>(&wlds[(k<<7)+(ty<<3)]);
      float4 w1 = *reinterpret_cast<const float4*>(&wlds[(k<<7)+(ty<<3)+4]);
      float yv[8];
      #pragma unroll
      for (int i=0;i<8;i++) yv[i]=ylds[(tx*8+i)*33+k];
      #pragma unroll
      for (int i=0;i<8;i++){
        acc[i][0]=fmaf(yv[i],w0.x,acc[i][0]);
        acc[i][1]=fmaf(yv[i],w0.y,acc[i][1]);
        acc[i][2]=fmaf(yv[i],w0.z,acc[i][2]);
        acc[i][3]=fmaf(yv[i],w0.w,acc[i][3]);
        acc[i][4]=fmaf(yv[i],w1.x,acc[i][4]);
        acc[i][5]=fmaf(yv[i],w1.y,acc[i][5]);
        acc[i][6]=fmaf(yv[i],w1.z,acc[i][6]);
        acc[i][7]=fmaf(yv[i],w1.w,acc[i][7]);
      }
    }
    __syncthreads();
  }
  // epilogue: bias, stats, write F (pre-BN, external dtype) in output layout
  const int bb  = (int)(loc0/(J_*T_));
  const int jj  = (int)((loc0/T_)%J_);
  const int tt0 = (int)(loc0%T_);
  float sum[8], sq[8];
  #pragma unroll
  for (int jc=0;jc<8;jc++){ sum[jc]=0.f; sq[jc]=0.f; }
  #pragma unroll
  for (int jc=0;jc<8;jc++){
    int ch = ty*8+jc;
    float fb = ldx<BF>(fus_b, ch);
    size_t fbase = (((size_t)(bb*128+ch))*J_ + jj)*T_ + tt0 + tx*8;
    #pragma unroll
    for (int i=0;i<8;i+=2){
      float v0=acc[i][jc]+fb, v1=acc[i+1][jc]+fb;
      sum[jc]+=v0+v1; sq[jc]+=v0*v0+v1*v1;
      if constexpr (BF){
        *reinterpret_cast<u32*>((u16*)F + fbase + i) = (u32)f2b(v0) | ((u32)f2b(v1)<<16);
      } else {
        *reinterpret_cast<float2*>((float*)F + fbase + i) = make_float2(v0,v1);
      }
    }
  }
  float* red = wlds;  // safe: all threads past last k-loop barrier
  #pragma unroll
  for (int jc=0;jc<8;jc++){ red[(ty*16+tx)*16+jc]=sum[jc]; red[(ty*16+tx)*16+8+jc]=sq[jc]; }
  __syncthreads();
  {
    int tye = tid>>4, q = tid&15;
    float s=0.f;
    for (int t2=0;t2<16;t2++) s += red[(tye*16+t2)*16+q];
    int ch = tye*8 + (q&7), which = q>>3;
    atomicAdd(&statsF[(blk&63)*256 + ch*2 + which], s);
  }
}

// K4: finalize fus BN scale/shift
template<bool BF>
__global__ __launch_bounds__(256) void k4_finF(const u32* __restrict__ flag,
    const float* __restrict__ statsF,
    const void* __restrict__ fus_g, const void* __restrict__ fus_beta,
    float* __restrict__ scaleF, float* __restrict__ shiftF)
{
  if (*flag != (BF?1u:0u)) return;
  int ch = threadIdx.x;
  if (ch < 128){
    float s=0.f,q=0.f;
    for (int slot=0;slot<64;slot++){ s+=statsF[slot*256+ch*2]; q+=statsF[slot*256+ch*2+1]; }
    float m=s/NSTATF_;
    float v=fmaxf(q/NSTATF_-m*m,0.f);
    float r=rsqrtf(v+1e-5f);
    float g=ldx<BF>(fus_g,ch), be=ldx<BF>(fus_beta,ch);
    scaleF[ch]=r*g; shiftF[ch]=be - m*r*g;
  }
}

// K5: elementwise BN+ReLU in place on d_out (which holds pre-BN F).
// fp32 variant: 4 floats/thread; bf16 variant: 8 bf16/thread.
template<bool BF>
__global__ __launch_bounds__(256) void k5_out(const u32* __restrict__ flag,
    const float* __restrict__ scaleF, const float* __restrict__ shiftF, void* __restrict__ out)
{
  if (*flag != (BF?1u:0u)) return;
  if constexpr (BF){
    size_t idx = ((size_t)blockIdx.x*256 + threadIdx.x)*8;
    int ch = (int)((idx/(J_*T_)) & 127);
    float sc = scaleF[ch], sh = shiftF[ch];
    u16* o16 = (u16*)out;
    uint4 u = *reinterpret_cast<const uint4*>(o16 + idx);
    u32 w[4] = {u.x,u.y,u.z,u.w};
    u32 o[4];
    #pragma unroll
    for (int q=0;q<4;q++){
      float v0=fmaxf(fmaf(b2f((u16)(w[q]&0xffff)),sc,sh),0.f);
      float v1=fmaxf(fmaf(b2f((u16)(w[q]>>16)),sc,sh),0.f);
      o[q]=(u32)f2b(v0) | ((u32)f2b(v1)<<16);
    }
    *reinterpret_cast<uint4*>(o16 + idx) = make_uint4(o[0],o[1],o[2],o[3]);
  } else {
    size_t idx = ((size_t)blockIdx.x*256 + threadIdx.x)*4;
    int ch = (int)((idx/(J_*T_)) & 127);
    float sc = scaleF[ch], sh = shiftF[ch];
    float* of = (float*)out;
    float4 v = *reinterpret_cast<const float4*>(of + idx);
    v.x=fmaxf(fmaf(v.x,sc,sh),0.f);
    v.y=fmaxf(fmaf(v.y,sc,sh),0.f);
    v.z=fmaxf(fmaf(v.z,sc,sh),0.f);
    v.w=fmaxf(fmaf(v.w,sc,sh),0.f);
    *reinterpret_cast<float4*>(of + idx) = v;
  }
}

extern "C" void kernel_launch(void* const* d_in, const int* in_sizes, int n_in,
                              void* d_out, int out_size, void* d_ws, size_t ws_size,
                              hipStream_t stream)
{
  const void* x        = d_in[0];
  const int*  path     = (const int*)d_in[1];
  const void* raw_w    = d_in[2];
  const void* raw_b    = d_in[3];
  const void* raw_g    = d_in[4];
  const void* raw_beta = d_in[5];
  const void* ps_w     = d_in[6];
  const void* ps_b     = d_in[7];
  const void* ps_g     = d_in[8];
  const void* ps_beta  = d_in[9];
  const void* fus_w    = d_in[10];
  const void* fus_b    = d_in[11];
  const void* fus_g    = d_in[12];
  const void* fus_beta = d_in[13];

  char* w = (char*)d_ws;
  u32*   flag   = (u32*)w;   w += 256;
  float* statsY = (float*)w; w += 64*512*4;
  float* statsF = (float*)w; w += 64*256*4;
  float* psT    = (float*)w; w += KPS_*128*4;
  float* fusT   = (float*)w; w += 256*128*4;
  float* scaleY = (float*)w; w += 1024;
  float* shiftY = (float*)w; w += 1024;
  float* scaleF = (float*)w; w += 512;
  float* shiftF = (float*)w; w += 512;
  size_t off = (size_t)(w - (char*)d_ws);
  off = (off + 255) & ~(size_t)255;
  u16* Y = (u16*)((char*)d_ws + off);
  size_t avail = (ws_size > off) ? (ws_size - off) : 0;

  // chunk Y (bf16, 184.5 MB full) over batch so it fits in ws: c in {1,2,4,...,64}
  const size_t Yfull = (size_t)NLOC_*256*2;
  int c = 1;
  while (c < 64 && Yfull/(size_t)c > avail) c <<= 1;
  const int chunkLoc = NLOC_ / c;

  kdet<<<dim3(1),dim3(256),0,stream>>>((const u32*)x, flag);
  k0a_zero<<<dim3(64),dim3(256),0,stream>>>(statsY, statsF);
  k0b_tr<false><<<dim3(64),dim3(256),0,stream>>>(flag, ps_w, fus_w, psT, fusT);
  k0b_tr<true ><<<dim3(64),dim3(256),0,stream>>>(flag, ps_w, fus_w, psT, fusT);

  // phase A: stats for all chunks; keep Y only for the last chunk
  for (int i=0;i<c;i++){
    int wy = (i==c-1)?1:0;
    k1_sig_conv<false><<<dim3(chunkLoc/64),dim3(256),0,stream>>>(flag, x, path, raw_w, raw_b, ps_b, psT, Y, statsY, i*chunkLoc, wy, 1);
    k1_sig_conv<true ><<<dim3(chunkLoc/64),dim3(256),0,stream>>>(flag, x, path, raw_w, raw_b, ps_b, psT, Y, statsY, i*chunkLoc, wy, 1);
  }
  k2_finY<false><<<dim3(1),dim3(256),0,stream>>>(flag, statsY, raw_g, raw_beta, ps_g, ps_beta, scaleY, shiftY);
  k2_finY<true ><<<dim3(1),dim3(256),0,stream>>>(flag, statsY, raw_g, raw_beta, ps_g, ps_beta, scaleY, shiftY);

  // phase B: consume last chunk's Y first, then recompute+consume the others
  k3_fus<false><<<dim3(chunkLoc/128),dim3(256),0,stream>>>(flag, Y, fusT, scaleY, shiftY, fus_b, d_out, statsF, (c-1)*chunkLoc);
  k3_fus<true ><<<dim3(chunkLoc/128),dim3(256),0,stream>>>(flag, Y, fusT, scaleY, shiftY, fus_b, d_out, statsF, (c-1)*chunkLoc);
  for (int i=0;i<c-1;i++){
    k1_sig_conv<false><<<dim3(chunkLoc/64),dim3(256),0,stream>>>(flag, x, path, raw_w, raw_b, ps_b, psT, Y, statsY, i*chunkLoc, 1, 0);
    k1_sig_conv<true ><<<dim3(chunkLoc/64),dim3(256),0,stream>>>(flag, x, path, raw_w, raw_b, ps_b, psT, Y, statsY, i*chunkLoc, 1, 0);
    k3_fus<false><<<dim3(chunkLoc/128),dim3(256),0,stream>>>(flag, Y, fusT, scaleY, shiftY, fus_b, d_out, statsF, i*chunkLoc);
    k3_fus<true ><<<dim3(chunkLoc/128),dim3(256),0,stream>>>(flag, Y, fusT, scaleY, shiftY, fus_b, d_out, statsF, i*chunkLoc);
  }
  k4_finF<false><<<dim3(1),dim3(256),0,stream>>>(flag, statsF, fus_g, fus_beta, scaleF, shiftF);
  k4_finF<true ><<<dim3(1),dim3(256),0,stream>>>(flag, statsF, fus_g, fus_beta, scaleF, shiftF);
  k5_out<false><<<dim3(NLOC_*128/(256*4)),dim3(256),0,stream>>>(flag, scaleF, shiftF, d_out);
  k5_out<true ><<<dim3(NLOC_*128/(256*8)),dim3(256),0,stream>>>(flag, scaleF, shiftF, d_out);
}